// Round 6
// baseline (357.943 us; speedup 1.0000x reference)
//
#include <hip/hip_runtime.h>

#define NIN 784
#define H0 256
#define H1 128
#define H2 64
#define H3 32
#define NOUT 10
#define BATCH 128
#define TT 500
#define KCH0 25
#define JTILES 16

// LDS pads: spike rows (bf16) stride ≡4 mod 32 banks; cur rows (fp32) ≡1 mod 32
#define SW1 136
#define SW2 72
#define SW3 40
#define CW1 129
#define CW2 65
#define CW3 33
#define CW4 17

// d_out offsets (floats)
#define H1_OFF (BATCH * H0 * TT)
#define H2_OFF (H1_OFF + BATCH * H1 * TT)
#define H3_OFF (H2_OFF + BATCH * H2 * TT)
#define OUT_OFF (H3_OFF + BATCH * H3 * TT)
#define RATE_OFF (OUT_OFF + BATCH * NOUT * TT)

typedef __attribute__((ext_vector_type(8))) short short8v;
typedef __attribute__((ext_vector_type(4))) float f32x4;

__device__ __forceinline__ unsigned short f2bf(float f) {
  union { float f; unsigned u; } v; v.f = f;
  unsigned r = v.u + 0x7FFFu + ((v.u >> 16) & 1u);  // RNE
  return (unsigned short)(r >> 16);
}
__device__ __forceinline__ float bf2f(unsigned short b) {
  union { unsigned u; float f; } v; v.u = ((unsigned)b) << 16;
  return v.f;
}

// LIF step, shortened dependent chain: E=e^{-x}, s=1/(1+E), v*(1-s)=v*E/(1+E).
__device__ __forceinline__ float lif_step(float& v, float c) {
  v = 0.5f * (v + c);
  const float E = __expf(5.0f * (1.0f - v));
  const float r = 1.0f / (1.0f + E);
  v = v * E * r;
  return r;  // = s
}

// ---------------- pack_all: w0 -> A-frags, w1..w4 -> B-frags (verified) -------
__global__ void pack_all(const float* __restrict__ w0, const float* __restrict__ w1,
                         const float* __restrict__ w2, const float* __restrict__ w3,
                         const float* __restrict__ w4, unsigned short* __restrict__ Wf,
                         unsigned short* __restrict__ Bf) {
  const int bid = blockIdx.x, l = threadIdx.x;
  if (bid < JTILES * KCH0) {
    const int jt = bid / KCH0, kc = bid % KCH0;
    const int j = jt * 16 + (l & 15);
    const int kbase = kc * 32 + (l >> 4) * 8;
    unsigned v[4];
#pragma unroll
    for (int e = 0; e < 4; ++e) {
      const int k0 = kbase + e * 2;
      const float f0 = (k0 < NIN) ? fmaxf(w0[(size_t)k0 * H0 + j], 0.0f) : 0.0f;
      const float f1 = (k0 + 1 < NIN) ? fmaxf(w0[(size_t)(k0 + 1) * H0 + j], 0.0f) : 0.0f;
      v[e] = (unsigned)f2bf(f0) | ((unsigned)f2bf(f1) << 16);
    }
    uint4 o; o.x = v[0]; o.y = v[1]; o.z = v[2]; o.w = v[3];
    reinterpret_cast<uint4*>(Wf)[(size_t)bid * 64 + l] = o;
    return;
  }
  const int tile = bid - JTILES * KCH0;
  const float* w; int K, Nw, base, rel, KCH;
  if (tile < 64)      { w = w1; K = 256; Nw = 128; base = 0;        rel = tile;      KCH = 8; }
  else if (tile < 80) { w = w2; K = 128; Nw = 64;  base = 64 * 512; rel = tile - 64; KCH = 4; }
  else if (tile < 84) { w = w3; K = 64;  Nw = 32;  base = 80 * 512; rel = tile - 80; KCH = 2; }
  else                { w = w4; K = 32;  Nw = 10;  base = 84 * 512; rel = 0;         KCH = 1; }
  const int nt = rel / KCH, kc = rel % KCH;
  const int n = nt * 16 + (l & 15);
  const int kb = kc * 32 + (l >> 4) * 8;
  unsigned v[4];
#pragma unroll
  for (int e = 0; e < 4; ++e) {
    const int k0 = kb + e * 2;
    const float f0 = (n < Nw && k0 < K)     ? fmaxf(w[(size_t)k0 * Nw + n], 0.0f) : 0.0f;
    const float f1 = (n < Nw && k0 + 1 < K) ? fmaxf(w[(size_t)(k0 + 1) * Nw + n], 0.0f) : 0.0f;
    v[e] = (unsigned)f2bf(f0) | ((unsigned)f2bf(f1) << 16);
  }
  uint4 o; o.x = v[0]; o.y = v[1]; o.z = v[2]; o.w = v[3];
  *reinterpret_cast<uint4*>(Bf + base + ((size_t)rel * 64 + l) * 8) = o;
}

// ---------------- gemm0 (pipelined, __syncthreads; verified r3/r4) ------------
__global__ __launch_bounds__(256, 4) void gemm0(
    const float* __restrict__ X, const unsigned short* __restrict__ Wf,
    unsigned short* __restrict__ cur0) {
  const int ttile = blockIdx.x;
  const int b = blockIdx.y;
  const int tid = threadIdx.x;
  const int wave = tid >> 6, lane = tid & 63;
  const int t0 = ttile * 64;
  __shared__ unsigned short Xs[2][64 * 40];
  f32x4 acc[4][4];
#pragma unroll
  for (int i = 0; i < 4; ++i)
#pragma unroll
    for (int jj = 0; jj < 4; ++jj) acc[i][jj] = (f32x4)0.0f;

  const float* Xb = X + (size_t)b * NIN * TT;
  const int tt = tid & 63;
  const int kb = wave * 2;
  const int lrow = lane & 15, lgrp = lane >> 4;
  const int tgl = t0 + tt;
  const bool tin = tgl < TT;

  float r[8];
#pragma unroll
  for (int pp = 0; pp < 4; ++pp) {
    const int k = kb + pp * 8;
    r[pp * 2]     = tin ? Xb[(size_t)k * TT + tgl] : 0.0f;
    r[pp * 2 + 1] = tin ? Xb[(size_t)(k + 1) * TT + tgl] : 0.0f;
  }

  for (int kc = 0; kc < KCH0; ++kc) {
    unsigned short* xbuf = Xs[kc & 1];
#pragma unroll
    for (int pp = 0; pp < 4; ++pp) {
      const unsigned pk = (unsigned)f2bf(r[pp * 2]) | ((unsigned)f2bf(r[pp * 2 + 1]) << 16);
      *reinterpret_cast<unsigned*>(&xbuf[tt * 40 + kb + pp * 8]) = pk;
    }
    __syncthreads();
    if (kc + 1 < KCH0) {
      const int k0 = (kc + 1) * 32;
#pragma unroll
      for (int pp = 0; pp < 4; ++pp) {
        const int k = k0 + kb + pp * 8;
        r[pp * 2]     = (tin && k < NIN)     ? Xb[(size_t)k * TT + tgl] : 0.0f;
        r[pp * 2 + 1] = (tin && k + 1 < NIN) ? Xb[(size_t)(k + 1) * TT + tgl] : 0.0f;
      }
    }
    short8v afr[4], bfr[4];
#pragma unroll
    for (int jf = 0; jf < 4; ++jf) {
      const size_t off = ((size_t)((wave * 4 + jf) * KCH0 + kc) * 64 + lane) * 8;
      afr[jf] = *reinterpret_cast<const short8v*>(Wf + off);
    }
#pragma unroll
    for (int tf = 0; tf < 4; ++tf)
      bfr[tf] = *reinterpret_cast<const short8v*>(&xbuf[(tf * 16 + lrow) * 40 + lgrp * 8]);
#pragma unroll
    for (int jf = 0; jf < 4; ++jf)
#pragma unroll
      for (int tf = 0; tf < 4; ++tf)
        acc[jf][tf] = __builtin_amdgcn_mfma_f32_16x16x32_bf16(afr[jf], bfr[tf], acc[jf][tf], 0, 0, 0);
    __syncthreads();
  }

#pragma unroll
  for (int tf = 0; tf < 4; ++tf) {
    const int t = t0 + tf * 16 + lrow;
    if (t >= TT) continue;
    unsigned short* row = cur0 + ((size_t)b * TT + t) * H0;
#pragma unroll
    for (int jf = 0; jf < 4; ++jf) {
      const int j = wave * 64 + jf * 16 + lgrp * 4;
      const f32x4 a = acc[jf][tf];
      const unsigned p0 = (unsigned)f2bf(a[0]) | ((unsigned)f2bf(a[1]) << 16);
      const unsigned p1 = (unsigned)f2bf(a[2]) | ((unsigned)f2bf(a[3]) << 16);
      *reinterpret_cast<unsigned*>(row + j) = p0;
      *reinterpret_cast<unsigned*>(row + j + 2) = p1;
    }
  }
}

// ---------------- scan0 (standalone, full machine) ----------------------------
// s0g layout [b][tq][256] bf16, tq = t+1 (slot 0 = zeros), 512 slots.
__global__ __launch_bounds__(64) void scan0(
    const unsigned short* __restrict__ cur0, unsigned short* __restrict__ s0g,
    float* __restrict__ out) {
  const int b = blockIdx.y, jg = blockIdx.x, l = threadIdx.x;
  const int j = jg * 64 + l;
  const unsigned short* cp = cur0 + (size_t)b * TT * H0 + j;
  unsigned short* sp = s0g + (size_t)b * 512 * H0 + j;
  float* hp = out + ((size_t)b * H0 + j) * TT;
  sp[0] = 0;
  float v = 0.0f;
  float A[64], B[64];
#define LOADN(D, T0, N) _Pragma("unroll") for (int u = 0; u < (N); ++u) (D)[u] = bf2f(cp[(size_t)((T0) + u) * H0]);
#define PROCN(C, T0, N)                                                              \
  do {                                                                               \
    float hb[64];                                                                    \
    _Pragma("unroll")                                                                \
    for (int u = 0; u < (N); ++u) {                                                  \
      const float s = lif_step(v, (C)[u]);                                           \
      hb[u] = s;                                                                     \
      sp[(size_t)((T0) + u + 1) * H0] = f2bf(s);                                     \
    }                                                                                \
    _Pragma("unroll")                                                                \
    for (int q = 0; q < (N) / 4; ++q)                                                \
      *reinterpret_cast<float4*>(hp + (T0) + q * 4) =                                \
          make_float4(hb[q * 4], hb[q * 4 + 1], hb[q * 4 + 2], hb[q * 4 + 3]);       \
  } while (0)
  LOADN(A, 0, 64);
  LOADN(B, 64, 64);  PROCN(A, 0, 64);
  LOADN(A, 128, 64); PROCN(B, 64, 64);
  LOADN(B, 192, 64); PROCN(A, 128, 64);
  LOADN(A, 256, 64); PROCN(B, 192, 64);
  LOADN(B, 320, 64); PROCN(A, 256, 64);
  LOADN(A, 384, 64); PROCN(B, 320, 64);
  LOADN(B, 448, 52); PROCN(A, 384, 64);
  PROCN(B, 448, 52);
#undef LOADN
#undef PROCN
}

// layers 1..4: preload N currents from LDS into regs, then serial chain.
template<int N>
__device__ __forceinline__ void lif_dyn(float& v, float& rate, const float* cur, int cw,
                                        unsigned short* sd, int sw, float* hp, bool wsf) {
  float cr[16];
  const float* cp = cur;
#pragma unroll
  for (int u = 0; u < N; ++u) { cr[u] = *cp; cp += cw; }
  float hb[16];
  unsigned short* sp = sd;
#pragma unroll
  for (int u = 0; u < N; ++u) {
    const float s = lif_step(v, cr[u]);
    hb[u] = s;
    if (wsf) *sp = f2bf(s);
    sp += sw;
    rate += s;
  }
#pragma unroll
  for (int q = 0; q < N / 4; ++q)
    *reinterpret_cast<float4*>(hp + q * 4) =
        make_float4(hb[q * 4], hb[q * 4 + 1], hb[q * 4 + 2], hb[q * 4 + 3]);
}

// ---------------- snn_tail14: fused gemm1..4 + scan1..4 + rates ---------------
// 1 block per b, 512 thr. Phases p=0..11: scan part {l1@p-1, l2@p-2, l3@p-3,
// l4@p-4}, barrier, gemm part {g1@p, g2@p-1, g3@p-2, g4@p-3}, barrier.
// gemm1 A-frags read directly from global s0g (L2/L3-resident).
__global__ __launch_bounds__(512, 1) void snn_tail14(
    const unsigned short* __restrict__ s0g, const unsigned short* __restrict__ Bf,
    float* __restrict__ out) {
  __shared__ __align__(16) unsigned short s1b[65 * SW1];
  __shared__ __align__(16) unsigned short s2b[65 * SW2];
  __shared__ __align__(16) unsigned short s3b[65 * SW3];
  __shared__ __align__(16) float c1b[64 * CW1];
  __shared__ __align__(16) float c2b[64 * CW2];
  __shared__ __align__(16) float c3b[64 * CW3];
  __shared__ __align__(16) float c4b[64 * CW4];

  const int b = blockIdx.x, tid = threadIdx.x;
  const int w = tid >> 6, lane = tid & 63, lr = lane & 15, lg = lane >> 4;
  const unsigned short* BfW1 = Bf;
  const unsigned short* BfW2 = Bf + 64 * 512;
  const unsigned short* BfW3 = Bf + 80 * 512;
  const unsigned short* BfW4 = Bf + 84 * 512;
  const unsigned short* s0b = s0g + (size_t)b * 512 * H0;

  float v = 0.0f, rate = 0.0f;
  int lay = 0, j = 0;
  const float* curb = nullptr;
  unsigned short* sb = s3b;
  float* hbase = nullptr;
  int cw = 0, sw = 0;
  bool wsf = false, sact = false;
  if (tid < 128) {
    lay = 1; j = tid; curb = c1b + j; sb = s1b; cw = CW1; sw = SW1; wsf = true;
    sact = true; hbase = out + H1_OFF + ((size_t)b * H1 + j) * TT;
  } else if (tid < 192) {
    lay = 2; j = tid - 128; curb = c2b + j; sb = s2b; cw = CW2; sw = SW2; wsf = true;
    sact = true; hbase = out + H2_OFF + ((size_t)b * H2 + j) * TT;
  } else if (tid < 224) {
    lay = 3; j = tid - 192; curb = c3b + j; sb = s3b; cw = CW3; sw = SW3; wsf = true;
    sact = true; hbase = out + H3_OFF + ((size_t)b * H3 + j) * TT;
  } else if (tid < 240) {
    lay = 4; j = tid - 224; curb = c4b + j; sb = s3b; cw = CW4; sw = 0; wsf = false;
    sact = (j < NOUT); hbase = out + OUT_OFF + ((size_t)b * NOUT + j) * TT;
  }

  for (int p = 0; p < 12; ++p) {
    // ================= scan part =================
    if (sact) {
      const int c = p - lay;
      if (c >= 0 && c <= 7) {
        if (wsf) sb[j] = (c == 0) ? (unsigned short)0 : sb[64 * sw + j];
        float* hp = hbase + c * 64;
        unsigned short* sbj = sb + j;
        if (c < 7) {
#pragma unroll
          for (int q = 0; q < 4; ++q)
            lif_dyn<16>(v, rate, curb + q * 16 * cw, cw, sbj + (q * 16 + 1) * sw, sw,
                        hp + q * 16, wsf);
        } else {
          lif_dyn<16>(v, rate, curb, cw, sbj + 1 * sw, sw, hp, wsf);
          lif_dyn<16>(v, rate, curb + 16 * cw, cw, sbj + 17 * sw, sw, hp + 16, wsf);
          lif_dyn<16>(v, rate, curb + 32 * cw, cw, sbj + 33 * sw, sw, hp + 32, wsf);
          lif_dyn<4>(v, rate, curb + 48 * cw, cw, sbj + 49 * sw, sw, hp + 48, wsf);
        }
      }
    }
    __syncthreads();
    // ================= gemm part =================
    if (p <= 7) {  // gemm1: s0g chunk p -> c1b. A rows tq = p*64 + 0..63.
      const int tt = w >> 1, nb = (w & 1) * 4;
      short8v a[8];
      const unsigned short* ap = s0b + (size_t)(p * 64 + tt * 16 + lr) * H0 + lg * 8;
#pragma unroll
      for (int kc = 0; kc < 8; ++kc) a[kc] = *reinterpret_cast<const short8v*>(ap + kc * 32);
#pragma unroll
      for (int n4 = 0; n4 < 4; ++n4) {
        const int nt = nb + n4;
        f32x4 acc = (f32x4)0.0f;
#pragma unroll
        for (int kc = 0; kc < 8; ++kc) {
          const short8v bf = *reinterpret_cast<const short8v*>(BfW1 + ((size_t)(nt * 8 + kc) * 64 + lane) * 8);
          acc = __builtin_amdgcn_mfma_f32_16x16x32_bf16(a[kc], bf, acc, 0, 0, 0);
        }
        float* cd = c1b + (tt * 16 + lg * 4) * CW1 + nt * 16 + lr;
#pragma unroll
        for (int r = 0; r < 4; ++r) cd[r * CW1] = acc[r];
      }
    }
    if (p >= 1 && p <= 8) {  // gemm2: s1b -> c2b
      const int tt = w >> 1;
      short8v a[4];
      const unsigned short* ap = s1b + (tt * 16 + lr) * SW1 + lg * 8;
#pragma unroll
      for (int kc = 0; kc < 4; ++kc) a[kc] = *reinterpret_cast<const short8v*>(ap + kc * 32);
#pragma unroll
      for (int qi = 0; qi < 2; ++qi) {
        const int nt = (w & 1) * 2 + qi;
        f32x4 acc = (f32x4)0.0f;
#pragma unroll
        for (int kc = 0; kc < 4; ++kc) {
          const short8v bf = *reinterpret_cast<const short8v*>(BfW2 + ((size_t)(nt * 4 + kc) * 64 + lane) * 8);
          acc = __builtin_amdgcn_mfma_f32_16x16x32_bf16(a[kc], bf, acc, 0, 0, 0);
        }
        float* cd = c2b + (tt * 16 + lg * 4) * CW2 + nt * 16 + lr;
#pragma unroll
        for (int r = 0; r < 4; ++r) cd[r * CW2] = acc[r];
      }
    }
    if (p >= 2 && p <= 9) {  // gemm3: s2b -> c3b
      const int tt = w >> 1, nt = w & 1;
      short8v a[2];
      const unsigned short* ap = s2b + (tt * 16 + lr) * SW2 + lg * 8;
#pragma unroll
      for (int kc = 0; kc < 2; ++kc) a[kc] = *reinterpret_cast<const short8v*>(ap + kc * 32);
      f32x4 acc = (f32x4)0.0f;
#pragma unroll
      for (int kc = 0; kc < 2; ++kc) {
        const short8v bf = *reinterpret_cast<const short8v*>(BfW3 + ((size_t)(nt * 2 + kc) * 64 + lane) * 8);
        acc = __builtin_amdgcn_mfma_f32_16x16x32_bf16(a[kc], bf, acc, 0, 0, 0);
      }
      float* cd = c3b + (tt * 16 + lg * 4) * CW3 + nt * 16 + lr;
#pragma unroll
      for (int r = 0; r < 4; ++r) cd[r * CW3] = acc[r];
    }
    if (p >= 3 && p <= 10 && w < 4) {  // gemm4: s3b -> c4b
      const int tt = w;
      const unsigned short* ap = s3b + (tt * 16 + lr) * SW3 + lg * 8;
      const short8v a0 = *reinterpret_cast<const short8v*>(ap);
      const short8v bf = *reinterpret_cast<const short8v*>(BfW4 + (size_t)lane * 8);
      f32x4 acc = (f32x4)0.0f;
      acc = __builtin_amdgcn_mfma_f32_16x16x32_bf16(a0, bf, acc, 0, 0, 0);
      float* cd = c4b + (tt * 16 + lg * 4) * CW4 + lr;
#pragma unroll
      for (int r = 0; r < 4; ++r) cd[r * CW4] = acc[r];
    }
    __syncthreads();
  }
  if (tid >= 224 && tid < 224 + NOUT)
    out[RATE_OFF + (size_t)b * NOUT + (tid - 224)] = rate * (1.0f / (float)TT);
}

extern "C" void kernel_launch(void* const* d_in, const int* in_sizes, int n_in,
                              void* d_out, int out_size, void* d_ws, size_t ws_size,
                              hipStream_t stream) {
  const float* X  = (const float*)d_in[0];
  const float* w0 = (const float*)d_in[1];
  const float* w1 = (const float*)d_in[2];
  const float* w2 = (const float*)d_in[3];
  const float* w3 = (const float*)d_in[4];
  const float* w4 = (const float*)d_in[5];
  float* out = (float*)d_out;

  uint8_t* ws = (uint8_t*)d_ws;
  const size_t SLOT = 33554432;
  unsigned short* cur0 = (unsigned short*)ws;                  // [b][TT][256] bf16
  unsigned short* s0g  = (unsigned short*)(ws + SLOT);         // [b][512][256] bf16
  unsigned short* Wf0  = (unsigned short*)(ws + 2 * SLOT);     // w0 A-frags
  unsigned short* Bf2  = Wf0 + (size_t)JTILES * KCH0 * 64 * 8; // w1..w4 B-frags

  pack_all<<<JTILES * KCH0 + 85, 64, 0, stream>>>(w0, w1, w2, w3, w4, Wf0, Bf2);
  gemm0<<<dim3(8, BATCH), 256, 0, stream>>>(X, Wf0, cur0);
  scan0<<<dim3(4, BATCH), 64, 0, stream>>>(cur0, s0g, out);
  snn_tail14<<<BATCH, 512, 0, stream>>>(s0g, Bf2, out);
}

// Round 7
// 233.418 us; speedup vs baseline: 1.5335x; 1.5335x over previous
//
#include <hip/hip_runtime.h>

#define NIN 784
#define H0 256
#define H1 128
#define H2 64
#define H3 32
#define NOUT 10
#define BATCH 128
#define TT 500
#define KCH0 25
#define JTILES 16

// LDS pads: spike rows (bf16) stride ≡4 mod 32 banks; cur rows (fp32) ≡1 mod 32
#define SW1 136
#define SW2 72
#define SW3 40
#define CW1 129
#define CW2 65
#define CW3 33
#define CW4 17

// d_out offsets (floats)
#define H1_OFF (BATCH * H0 * TT)
#define H2_OFF (H1_OFF + BATCH * H1 * TT)
#define H3_OFF (H2_OFF + BATCH * H2 * TT)
#define OUT_OFF (H3_OFF + BATCH * H3 * TT)
#define RATE_OFF (OUT_OFF + BATCH * NOUT * TT)

typedef __attribute__((ext_vector_type(8))) short short8v;
typedef __attribute__((ext_vector_type(4))) float f32x4;

__device__ __forceinline__ unsigned short f2bf(float f) {
  union { float f; unsigned u; } v; v.f = f;
  unsigned r = v.u + 0x7FFFu + ((v.u >> 16) & 1u);  // RNE
  return (unsigned short)(r >> 16);
}
__device__ __forceinline__ float bf2f(unsigned short b) {
  union { unsigned u; float f; } v; v.u = ((unsigned)b) << 16;
  return v.f;
}

// LIF step, shortened dependent chain: E=e^{-x}, s=1/(1+E), v*(1-s)=v*E/(1+E).
__device__ __forceinline__ float lif_step(float& v, float c) {
  v = 0.5f * (v + c);
  const float E = __expf(5.0f * (1.0f - v));
  const float r = 1.0f / (1.0f + E);
  v = v * E * r;
  return r;  // = s
}

// ---------------- pack_all: w0 -> A-frags, w1..w4 -> B-frags (verified) -------
__global__ void pack_all(const float* __restrict__ w0, const float* __restrict__ w1,
                         const float* __restrict__ w2, const float* __restrict__ w3,
                         const float* __restrict__ w4, unsigned short* __restrict__ Wf,
                         unsigned short* __restrict__ Bf) {
  const int bid = blockIdx.x, l = threadIdx.x;
  if (bid < JTILES * KCH0) {
    const int jt = bid / KCH0, kc = bid % KCH0;
    const int j = jt * 16 + (l & 15);
    const int kbase = kc * 32 + (l >> 4) * 8;
    unsigned v[4];
#pragma unroll
    for (int e = 0; e < 4; ++e) {
      const int k0 = kbase + e * 2;
      const float f0 = (k0 < NIN) ? fmaxf(w0[(size_t)k0 * H0 + j], 0.0f) : 0.0f;
      const float f1 = (k0 + 1 < NIN) ? fmaxf(w0[(size_t)(k0 + 1) * H0 + j], 0.0f) : 0.0f;
      v[e] = (unsigned)f2bf(f0) | ((unsigned)f2bf(f1) << 16);
    }
    uint4 o; o.x = v[0]; o.y = v[1]; o.z = v[2]; o.w = v[3];
    reinterpret_cast<uint4*>(Wf)[(size_t)bid * 64 + l] = o;
    return;
  }
  const int tile = bid - JTILES * KCH0;
  const float* w; int K, Nw, base, rel, KCH;
  if (tile < 64)      { w = w1; K = 256; Nw = 128; base = 0;        rel = tile;      KCH = 8; }
  else if (tile < 80) { w = w2; K = 128; Nw = 64;  base = 64 * 512; rel = tile - 64; KCH = 4; }
  else if (tile < 84) { w = w3; K = 64;  Nw = 32;  base = 80 * 512; rel = tile - 80; KCH = 2; }
  else                { w = w4; K = 32;  Nw = 10;  base = 84 * 512; rel = 0;         KCH = 1; }
  const int nt = rel / KCH, kc = rel % KCH;
  const int n = nt * 16 + (l & 15);
  const int kb = kc * 32 + (l >> 4) * 8;
  unsigned v[4];
#pragma unroll
  for (int e = 0; e < 4; ++e) {
    const int k0 = kb + e * 2;
    const float f0 = (n < Nw && k0 < K)     ? fmaxf(w[(size_t)k0 * Nw + n], 0.0f) : 0.0f;
    const float f1 = (n < Nw && k0 + 1 < K) ? fmaxf(w[(size_t)(k0 + 1) * Nw + n], 0.0f) : 0.0f;
    v[e] = (unsigned)f2bf(f0) | ((unsigned)f2bf(f1) << 16);
  }
  uint4 o; o.x = v[0]; o.y = v[1]; o.z = v[2]; o.w = v[3];
  *reinterpret_cast<uint4*>(Bf + base + ((size_t)rel * 64 + l) * 8) = o;
}

// ---------------- gemm0 (pipelined, __syncthreads; verified r3/r4) ------------
__global__ __launch_bounds__(256, 4) void gemm0(
    const float* __restrict__ X, const unsigned short* __restrict__ Wf,
    unsigned short* __restrict__ cur0) {
  const int ttile = blockIdx.x;
  const int b = blockIdx.y;
  const int tid = threadIdx.x;
  const int wave = tid >> 6, lane = tid & 63;
  const int t0 = ttile * 64;
  __shared__ unsigned short Xs[2][64 * 40];
  f32x4 acc[4][4];
#pragma unroll
  for (int i = 0; i < 4; ++i)
#pragma unroll
    for (int jj = 0; jj < 4; ++jj) acc[i][jj] = (f32x4)0.0f;

  const float* Xb = X + (size_t)b * NIN * TT;
  const int tt = tid & 63;
  const int kb = wave * 2;
  const int lrow = lane & 15, lgrp = lane >> 4;
  const int tgl = t0 + tt;
  const bool tin = tgl < TT;

  float r[8];
#pragma unroll
  for (int pp = 0; pp < 4; ++pp) {
    const int k = kb + pp * 8;
    r[pp * 2]     = tin ? Xb[(size_t)k * TT + tgl] : 0.0f;
    r[pp * 2 + 1] = tin ? Xb[(size_t)(k + 1) * TT + tgl] : 0.0f;
  }

  for (int kc = 0; kc < KCH0; ++kc) {
    unsigned short* xbuf = Xs[kc & 1];
#pragma unroll
    for (int pp = 0; pp < 4; ++pp) {
      const unsigned pk = (unsigned)f2bf(r[pp * 2]) | ((unsigned)f2bf(r[pp * 2 + 1]) << 16);
      *reinterpret_cast<unsigned*>(&xbuf[tt * 40 + kb + pp * 8]) = pk;
    }
    __syncthreads();
    if (kc + 1 < KCH0) {
      const int k0 = (kc + 1) * 32;
#pragma unroll
      for (int pp = 0; pp < 4; ++pp) {
        const int k = k0 + kb + pp * 8;
        r[pp * 2]     = (tin && k < NIN)     ? Xb[(size_t)k * TT + tgl] : 0.0f;
        r[pp * 2 + 1] = (tin && k + 1 < NIN) ? Xb[(size_t)(k + 1) * TT + tgl] : 0.0f;
      }
    }
    short8v afr[4], bfr[4];
#pragma unroll
    for (int jf = 0; jf < 4; ++jf) {
      const size_t off = ((size_t)((wave * 4 + jf) * KCH0 + kc) * 64 + lane) * 8;
      afr[jf] = *reinterpret_cast<const short8v*>(Wf + off);
    }
#pragma unroll
    for (int tf = 0; tf < 4; ++tf)
      bfr[tf] = *reinterpret_cast<const short8v*>(&xbuf[(tf * 16 + lrow) * 40 + lgrp * 8]);
#pragma unroll
    for (int jf = 0; jf < 4; ++jf)
#pragma unroll
      for (int tf = 0; tf < 4; ++tf)
        acc[jf][tf] = __builtin_amdgcn_mfma_f32_16x16x32_bf16(afr[jf], bfr[tf], acc[jf][tf], 0, 0, 0);
    __syncthreads();
  }

#pragma unroll
  for (int tf = 0; tf < 4; ++tf) {
    const int t = t0 + tf * 16 + lrow;
    if (t >= TT) continue;
    unsigned short* row = cur0 + ((size_t)b * TT + t) * H0;
#pragma unroll
    for (int jf = 0; jf < 4; ++jf) {
      const int j = wave * 64 + jf * 16 + lgrp * 4;
      const f32x4 a = acc[jf][tf];
      const unsigned p0 = (unsigned)f2bf(a[0]) | ((unsigned)f2bf(a[1]) << 16);
      const unsigned p1 = (unsigned)f2bf(a[2]) | ((unsigned)f2bf(a[3]) << 16);
      *reinterpret_cast<unsigned*>(row + j) = p0;
      *reinterpret_cast<unsigned*>(row + j + 2) = p1;
    }
  }
}

// ---------------- scan0 (standalone; 16-deep ping-pong, no spills) ------------
// s0g layout [b][tq][256] bf16, tq = t+1 (slot 0 = zeros), 512 slots.
__global__ __launch_bounds__(64) void scan0(
    const unsigned short* __restrict__ cur0, unsigned short* __restrict__ s0g,
    float* __restrict__ out) {
  const int b = blockIdx.y, jg = blockIdx.x, l = threadIdx.x;
  const int j = jg * 64 + l;
  const unsigned short* cp = cur0 + (size_t)b * TT * H0 + j;
  unsigned short* sp = s0g + (size_t)b * 512 * H0 + j;
  float* hp = out + ((size_t)b * H0 + j) * TT;
  sp[0] = 0;
  float v = 0.0f;
  float c0[16], c1[16];
#define LOAD16(D, T0) _Pragma("unroll") for (int u = 0; u < 16; ++u) (D)[u] = bf2f(cp[(size_t)((T0) + u) * H0]);
#define PROC16(C, T0)                                                                \
  do {                                                                               \
    float hb[16];                                                                    \
    _Pragma("unroll")                                                                \
    for (int u = 0; u < 16; ++u) {                                                   \
      const float s = lif_step(v, (C)[u]);                                           \
      hb[u] = s;                                                                     \
      sp[(size_t)((T0) + u + 1) * H0] = f2bf(s);                                     \
    }                                                                                \
    _Pragma("unroll")                                                                \
    for (int q = 0; q < 4; ++q)                                                      \
      *reinterpret_cast<float4*>(hp + (T0) + q * 4) =                                \
          make_float4(hb[q * 4], hb[q * 4 + 1], hb[q * 4 + 2], hb[q * 4 + 3]);       \
  } while (0)
  LOAD16(c0, 0);
  for (int i = 0; i < 15; ++i) {
    const int tb = i * 32;
    LOAD16(c1, tb + 16);
    PROC16(c0, tb);
    LOAD16(c0, tb + 32);
    PROC16(c1, tb + 16);
  }
  PROC16(c0, 480);
  {  // tail t = 496..499
    float c[4], hb[4];
#pragma unroll
    for (int u = 0; u < 4; ++u) c[u] = bf2f(cp[(size_t)(496 + u) * H0]);
#pragma unroll
    for (int u = 0; u < 4; ++u) {
      const float s = lif_step(v, c[u]);
      hb[u] = s;
      sp[(size_t)(496 + u + 1) * H0] = f2bf(s);
    }
    *reinterpret_cast<float4*>(hp + 496) = make_float4(hb[0], hb[1], hb[2], hb[3]);
  }
#undef LOAD16
#undef PROC16
}

// layers 1..4: preload N currents from LDS into regs, then serial chain.
template<int N>
__device__ __forceinline__ void lif_dyn(float& v, float& rate, const float* cur, int cw,
                                        unsigned short* sd, int sw, float* hp, bool wsf) {
  float cr[16];
  const float* cp = cur;
#pragma unroll
  for (int u = 0; u < N; ++u) { cr[u] = *cp; cp += cw; }
  float hb[16];
  unsigned short* sp = sd;
#pragma unroll
  for (int u = 0; u < N; ++u) {
    const float s = lif_step(v, cr[u]);
    hb[u] = s;
    if (wsf) *sp = f2bf(s);
    sp += sw;
    rate += s;
  }
#pragma unroll
  for (int q = 0; q < N / 4; ++q)
    *reinterpret_cast<float4*>(hp + q * 4) =
        make_float4(hb[q * 4], hb[q * 4 + 1], hb[q * 4 + 2], hb[q * 4 + 3]);
}

// ---------------- snn_tail14: fused gemm1..4 + scan1..4 + rates ---------------
__global__ __launch_bounds__(512, 1) void snn_tail14(
    const unsigned short* __restrict__ s0g, const unsigned short* __restrict__ Bf,
    float* __restrict__ out) {
  __shared__ __align__(16) unsigned short s1b[65 * SW1];
  __shared__ __align__(16) unsigned short s2b[65 * SW2];
  __shared__ __align__(16) unsigned short s3b[65 * SW3];
  __shared__ __align__(16) float c1b[64 * CW1];
  __shared__ __align__(16) float c2b[64 * CW2];
  __shared__ __align__(16) float c3b[64 * CW3];
  __shared__ __align__(16) float c4b[64 * CW4];

  const int b = blockIdx.x, tid = threadIdx.x;
  const int w = tid >> 6, lane = tid & 63, lr = lane & 15, lg = lane >> 4;
  const unsigned short* BfW1 = Bf;
  const unsigned short* BfW2 = Bf + 64 * 512;
  const unsigned short* BfW3 = Bf + 80 * 512;
  const unsigned short* BfW4 = Bf + 84 * 512;
  const unsigned short* s0b = s0g + (size_t)b * 512 * H0;

  float v = 0.0f, rate = 0.0f;
  int lay = 0, j = 0;
  const float* curb = nullptr;
  unsigned short* sb = s3b;
  float* hbase = nullptr;
  int cw = 0, sw = 0;
  bool wsf = false, sact = false;
  if (tid < 128) {
    lay = 1; j = tid; curb = c1b + j; sb = s1b; cw = CW1; sw = SW1; wsf = true;
    sact = true; hbase = out + H1_OFF + ((size_t)b * H1 + j) * TT;
  } else if (tid < 192) {
    lay = 2; j = tid - 128; curb = c2b + j; sb = s2b; cw = CW2; sw = SW2; wsf = true;
    sact = true; hbase = out + H2_OFF + ((size_t)b * H2 + j) * TT;
  } else if (tid < 224) {
    lay = 3; j = tid - 192; curb = c3b + j; sb = s3b; cw = CW3; sw = SW3; wsf = true;
    sact = true; hbase = out + H3_OFF + ((size_t)b * H3 + j) * TT;
  } else if (tid < 240) {
    lay = 4; j = tid - 224; curb = c4b + j; sb = s3b; cw = CW4; sw = 0; wsf = false;
    sact = (j < NOUT); hbase = out + OUT_OFF + ((size_t)b * NOUT + j) * TT;
  }

  for (int p = 0; p < 12; ++p) {
    // ================= scan part =================
    if (sact) {
      const int c = p - lay;
      if (c >= 0 && c <= 7) {
        if (wsf) sb[j] = (c == 0) ? (unsigned short)0 : sb[64 * sw + j];
        float* hp = hbase + c * 64;
        unsigned short* sbj = sb + j;
        if (c < 7) {
#pragma unroll
          for (int q = 0; q < 4; ++q)
            lif_dyn<16>(v, rate, curb + q * 16 * cw, cw, sbj + (q * 16 + 1) * sw, sw,
                        hp + q * 16, wsf);
        } else {
          lif_dyn<16>(v, rate, curb, cw, sbj + 1 * sw, sw, hp, wsf);
          lif_dyn<16>(v, rate, curb + 16 * cw, cw, sbj + 17 * sw, sw, hp + 16, wsf);
          lif_dyn<16>(v, rate, curb + 32 * cw, cw, sbj + 33 * sw, sw, hp + 32, wsf);
          lif_dyn<4>(v, rate, curb + 48 * cw, cw, sbj + 49 * sw, sw, hp + 48, wsf);
        }
      }
    }
    __syncthreads();
    // ================= gemm part =================
    if (p <= 7) {  // gemm1: s0g chunk p -> c1b. A rows tq = p*64 + 0..63.
      const int tt = w >> 1, nb = (w & 1) * 4;
      short8v a[8];
      const unsigned short* ap = s0b + (size_t)(p * 64 + tt * 16 + lr) * H0 + lg * 8;
#pragma unroll
      for (int kc = 0; kc < 8; ++kc) a[kc] = *reinterpret_cast<const short8v*>(ap + kc * 32);
#pragma unroll
      for (int n4 = 0; n4 < 4; ++n4) {
        const int nt = nb + n4;
        f32x4 acc = (f32x4)0.0f;
#pragma unroll
        for (int kc = 0; kc < 8; ++kc) {
          const short8v bf = *reinterpret_cast<const short8v*>(BfW1 + ((size_t)(nt * 8 + kc) * 64 + lane) * 8);
          acc = __builtin_amdgcn_mfma_f32_16x16x32_bf16(a[kc], bf, acc, 0, 0, 0);
        }
        float* cd = c1b + (tt * 16 + lg * 4) * CW1 + nt * 16 + lr;
#pragma unroll
        for (int r = 0; r < 4; ++r) cd[r * CW1] = acc[r];
      }
    }
    if (p >= 1 && p <= 8) {  // gemm2: s1b -> c2b
      const int tt = w >> 1;
      short8v a[4];
      const unsigned short* ap = s1b + (tt * 16 + lr) * SW1 + lg * 8;
#pragma unroll
      for (int kc = 0; kc < 4; ++kc) a[kc] = *reinterpret_cast<const short8v*>(ap + kc * 32);
#pragma unroll
      for (int qi = 0; qi < 2; ++qi) {
        const int nt = (w & 1) * 2 + qi;
        f32x4 acc = (f32x4)0.0f;
#pragma unroll
        for (int kc = 0; kc < 4; ++kc) {
          const short8v bf = *reinterpret_cast<const short8v*>(BfW2 + ((size_t)(nt * 4 + kc) * 64 + lane) * 8);
          acc = __builtin_amdgcn_mfma_f32_16x16x32_bf16(a[kc], bf, acc, 0, 0, 0);
        }
        float* cd = c2b + (tt * 16 + lg * 4) * CW2 + nt * 16 + lr;
#pragma unroll
        for (int r = 0; r < 4; ++r) cd[r * CW2] = acc[r];
      }
    }
    if (p >= 2 && p <= 9) {  // gemm3: s2b -> c3b
      const int tt = w >> 1, nt = w & 1;
      short8v a[2];
      const unsigned short* ap = s2b + (tt * 16 + lr) * SW2 + lg * 8;
#pragma unroll
      for (int kc = 0; kc < 2; ++kc) a[kc] = *reinterpret_cast<const short8v*>(ap + kc * 32);
      f32x4 acc = (f32x4)0.0f;
#pragma unroll
      for (int kc = 0; kc < 2; ++kc) {
        const short8v bf = *reinterpret_cast<const short8v*>(BfW3 + ((size_t)(nt * 2 + kc) * 64 + lane) * 8);
        acc = __builtin_amdgcn_mfma_f32_16x16x32_bf16(a[kc], bf, acc, 0, 0, 0);
      }
      float* cd = c3b + (tt * 16 + lg * 4) * CW3 + nt * 16 + lr;
#pragma unroll
      for (int r = 0; r < 4; ++r) cd[r * CW3] = acc[r];
    }
    if (p >= 3 && p <= 10 && w < 4) {  // gemm4: s3b -> c4b
      const int tt = w;
      const unsigned short* ap = s3b + (tt * 16 + lr) * SW3 + lg * 8;
      const short8v a0 = *reinterpret_cast<const short8v*>(ap);
      const short8v bf = *reinterpret_cast<const short8v*>(BfW4 + (size_t)lane * 8);
      f32x4 acc = (f32x4)0.0f;
      acc = __builtin_amdgcn_mfma_f32_16x16x32_bf16(a0, bf, acc, 0, 0, 0);
      float* cd = c4b + (tt * 16 + lg * 4) * CW4 + lr;
#pragma unroll
      for (int r = 0; r < 4; ++r) cd[r * CW4] = acc[r];
    }
    __syncthreads();
  }
  if (tid >= 224 && tid < 224 + NOUT)
    out[RATE_OFF + (size_t)b * NOUT + (tid - 224)] = rate * (1.0f / (float)TT);
}

extern "C" void kernel_launch(void* const* d_in, const int* in_sizes, int n_in,
                              void* d_out, int out_size, void* d_ws, size_t ws_size,
                              hipStream_t stream) {
  const float* X  = (const float*)d_in[0];
  const float* w0 = (const float*)d_in[1];
  const float* w1 = (const float*)d_in[2];
  const float* w2 = (const float*)d_in[3];
  const float* w3 = (const float*)d_in[4];
  const float* w4 = (const float*)d_in[5];
  float* out = (float*)d_out;

  uint8_t* ws = (uint8_t*)d_ws;
  const size_t SLOT = 33554432;
  unsigned short* cur0 = (unsigned short*)ws;                  // [b][TT][256] bf16
  unsigned short* s0g  = (unsigned short*)(ws + SLOT);         // [b][512][256] bf16
  unsigned short* Wf0  = (unsigned short*)(ws + 2 * SLOT);     // w0 A-frags
  unsigned short* Bf2  = Wf0 + (size_t)JTILES * KCH0 * 64 * 8; // w1..w4 B-frags

  pack_all<<<JTILES * KCH0 + 85, 64, 0, stream>>>(w0, w1, w2, w3, w4, Wf0, Bf2);
  gemm0<<<dim3(8, BATCH), 256, 0, stream>>>(X, Wf0, cur0);
  scan0<<<dim3(4, BATCH), 64, 0, stream>>>(cur0, s0g, out);
  snn_tail14<<<BATCH, 512, 0, stream>>>(s0g, Bf2, out);
}

// Round 8
// 218.192 us; speedup vs baseline: 1.6405x; 1.0698x over previous
//
#include <hip/hip_runtime.h>

#define NIN 784
#define H0 256
#define H1 128
#define H2 64
#define H3 32
#define NOUT 10
#define BATCH 128
#define TT 500
#define KCH0 25
#define JTILES 16

// LDS pads (all bf16 now): spike rows stride ≡4 mod 32 banks; cur rows padded +4
#define SW1 136
#define SW2 72
#define SW3 40
#define CW1 132
#define CW2 68
#define CW3 36
#define CW4 20

// d_out offsets (floats)
#define H1_OFF (BATCH * H0 * TT)
#define H2_OFF (H1_OFF + BATCH * H1 * TT)
#define H3_OFF (H2_OFF + BATCH * H2 * TT)
#define OUT_OFF (H3_OFF + BATCH * H3 * TT)
#define RATE_OFF (OUT_OFF + BATCH * NOUT * TT)

typedef __attribute__((ext_vector_type(8))) short short8v;
typedef __attribute__((ext_vector_type(4))) float f32x4;

__device__ __forceinline__ unsigned short f2bf(float f) {
  union { float f; unsigned u; } v; v.f = f;
  unsigned r = v.u + 0x7FFFu + ((v.u >> 16) & 1u);  // RNE
  return (unsigned short)(r >> 16);
}
__device__ __forceinline__ float bf2f(unsigned short b) {
  union { unsigned u; float f; } v; v.u = ((unsigned)b) << 16;
  return v.f;
}

// LIF step, shortened dependent chain: E=e^{-x}, s=1/(1+E), v*(1-s)=v*E/(1+E).
__device__ __forceinline__ float lif_step(float& v, float c) {
  v = 0.5f * (v + c);
  const float E = __expf(5.0f * (1.0f - v));
  const float r = 1.0f / (1.0f + E);
  v = v * E * r;
  return r;  // = s
}

// ---------------- pack_all: w0 -> A-frags, w1..w4 -> B-frags (verified) -------
__global__ void pack_all(const float* __restrict__ w0, const float* __restrict__ w1,
                         const float* __restrict__ w2, const float* __restrict__ w3,
                         const float* __restrict__ w4, unsigned short* __restrict__ Wf,
                         unsigned short* __restrict__ Bf) {
  const int bid = blockIdx.x, l = threadIdx.x;
  if (bid < JTILES * KCH0) {
    const int jt = bid / KCH0, kc = bid % KCH0;
    const int j = jt * 16 + (l & 15);
    const int kbase = kc * 32 + (l >> 4) * 8;
    unsigned v[4];
#pragma unroll
    for (int e = 0; e < 4; ++e) {
      const int k0 = kbase + e * 2;
      const float f0 = (k0 < NIN) ? fmaxf(w0[(size_t)k0 * H0 + j], 0.0f) : 0.0f;
      const float f1 = (k0 + 1 < NIN) ? fmaxf(w0[(size_t)(k0 + 1) * H0 + j], 0.0f) : 0.0f;
      v[e] = (unsigned)f2bf(f0) | ((unsigned)f2bf(f1) << 16);
    }
    uint4 o; o.x = v[0]; o.y = v[1]; o.z = v[2]; o.w = v[3];
    reinterpret_cast<uint4*>(Wf)[(size_t)bid * 64 + l] = o;
    return;
  }
  const int tile = bid - JTILES * KCH0;
  const float* w; int K, Nw, base, rel, KCH;
  if (tile < 64)      { w = w1; K = 256; Nw = 128; base = 0;        rel = tile;      KCH = 8; }
  else if (tile < 80) { w = w2; K = 128; Nw = 64;  base = 64 * 512; rel = tile - 64; KCH = 4; }
  else if (tile < 84) { w = w3; K = 64;  Nw = 32;  base = 80 * 512; rel = tile - 80; KCH = 2; }
  else                { w = w4; K = 32;  Nw = 10;  base = 84 * 512; rel = 0;         KCH = 1; }
  const int nt = rel / KCH, kc = rel % KCH;
  const int n = nt * 16 + (l & 15);
  const int kb = kc * 32 + (l >> 4) * 8;
  unsigned v[4];
#pragma unroll
  for (int e = 0; e < 4; ++e) {
    const int k0 = kb + e * 2;
    const float f0 = (n < Nw && k0 < K)     ? fmaxf(w[(size_t)k0 * Nw + n], 0.0f) : 0.0f;
    const float f1 = (n < Nw && k0 + 1 < K) ? fmaxf(w[(size_t)(k0 + 1) * Nw + n], 0.0f) : 0.0f;
    v[e] = (unsigned)f2bf(f0) | ((unsigned)f2bf(f1) << 16);
  }
  uint4 o; o.x = v[0]; o.y = v[1]; o.z = v[2]; o.w = v[3];
  *reinterpret_cast<uint4*>(Bf + base + ((size_t)rel * 64 + l) * 8) = o;
}

// ---------------- gemm0 (pipelined, __syncthreads; verified r3/r4) ------------
__global__ __launch_bounds__(256, 4) void gemm0(
    const float* __restrict__ X, const unsigned short* __restrict__ Wf,
    unsigned short* __restrict__ cur0) {
  const int ttile = blockIdx.x;
  const int b = blockIdx.y;
  const int tid = threadIdx.x;
  const int wave = tid >> 6, lane = tid & 63;
  const int t0 = ttile * 64;
  __shared__ unsigned short Xs[2][64 * 40];
  f32x4 acc[4][4];
#pragma unroll
  for (int i = 0; i < 4; ++i)
#pragma unroll
    for (int jj = 0; jj < 4; ++jj) acc[i][jj] = (f32x4)0.0f;

  const float* Xb = X + (size_t)b * NIN * TT;
  const int tt = tid & 63;
  const int kb = wave * 2;
  const int lrow = lane & 15, lgrp = lane >> 4;
  const int tgl = t0 + tt;
  const bool tin = tgl < TT;

  float r[8];
#pragma unroll
  for (int pp = 0; pp < 4; ++pp) {
    const int k = kb + pp * 8;
    r[pp * 2]     = tin ? Xb[(size_t)k * TT + tgl] : 0.0f;
    r[pp * 2 + 1] = tin ? Xb[(size_t)(k + 1) * TT + tgl] : 0.0f;
  }

  for (int kc = 0; kc < KCH0; ++kc) {
    unsigned short* xbuf = Xs[kc & 1];
#pragma unroll
    for (int pp = 0; pp < 4; ++pp) {
      const unsigned pk = (unsigned)f2bf(r[pp * 2]) | ((unsigned)f2bf(r[pp * 2 + 1]) << 16);
      *reinterpret_cast<unsigned*>(&xbuf[tt * 40 + kb + pp * 8]) = pk;
    }
    __syncthreads();
    if (kc + 1 < KCH0) {
      const int k0 = (kc + 1) * 32;
#pragma unroll
      for (int pp = 0; pp < 4; ++pp) {
        const int k = k0 + kb + pp * 8;
        r[pp * 2]     = (tin && k < NIN)     ? Xb[(size_t)k * TT + tgl] : 0.0f;
        r[pp * 2 + 1] = (tin && k + 1 < NIN) ? Xb[(size_t)(k + 1) * TT + tgl] : 0.0f;
      }
    }
    short8v afr[4], bfr[4];
#pragma unroll
    for (int jf = 0; jf < 4; ++jf) {
      const size_t off = ((size_t)((wave * 4 + jf) * KCH0 + kc) * 64 + lane) * 8;
      afr[jf] = *reinterpret_cast<const short8v*>(Wf + off);
    }
#pragma unroll
    for (int tf = 0; tf < 4; ++tf)
      bfr[tf] = *reinterpret_cast<const short8v*>(&xbuf[(tf * 16 + lrow) * 40 + lgrp * 8]);
#pragma unroll
    for (int jf = 0; jf < 4; ++jf)
#pragma unroll
      for (int tf = 0; tf < 4; ++tf)
        acc[jf][tf] = __builtin_amdgcn_mfma_f32_16x16x32_bf16(afr[jf], bfr[tf], acc[jf][tf], 0, 0, 0);
    __syncthreads();
  }

#pragma unroll
  for (int tf = 0; tf < 4; ++tf) {
    const int t = t0 + tf * 16 + lrow;
    if (t >= TT) continue;
    unsigned short* row = cur0 + ((size_t)b * TT + t) * H0;
#pragma unroll
    for (int jf = 0; jf < 4; ++jf) {
      const int j = wave * 64 + jf * 16 + lgrp * 4;
      const f32x4 a = acc[jf][tf];
      const unsigned p0 = (unsigned)f2bf(a[0]) | ((unsigned)f2bf(a[1]) << 16);
      const unsigned p1 = (unsigned)f2bf(a[2]) | ((unsigned)f2bf(a[3]) << 16);
      *reinterpret_cast<unsigned*>(row + j) = p0;
      *reinterpret_cast<unsigned*>(row + j + 2) = p1;
    }
  }
}

// ---------------- scan0 (standalone; 16-deep ping-pong, verified r7) ----------
__global__ __launch_bounds__(64) void scan0(
    const unsigned short* __restrict__ cur0, unsigned short* __restrict__ s0g,
    float* __restrict__ out) {
  const int b = blockIdx.y, jg = blockIdx.x, l = threadIdx.x;
  const int j = jg * 64 + l;
  const unsigned short* cp = cur0 + (size_t)b * TT * H0 + j;
  unsigned short* sp = s0g + (size_t)b * 512 * H0 + j;
  float* hp = out + ((size_t)b * H0 + j) * TT;
  sp[0] = 0;
  float v = 0.0f;
  float c0[16], c1[16];
#define LOAD16(D, T0) _Pragma("unroll") for (int u = 0; u < 16; ++u) (D)[u] = bf2f(cp[(size_t)((T0) + u) * H0]);
#define PROC16(C, T0)                                                                \
  do {                                                                               \
    float hb[16];                                                                    \
    _Pragma("unroll")                                                                \
    for (int u = 0; u < 16; ++u) {                                                   \
      const float s = lif_step(v, (C)[u]);                                           \
      hb[u] = s;                                                                     \
      sp[(size_t)((T0) + u + 1) * H0] = f2bf(s);                                     \
    }                                                                                \
    _Pragma("unroll")                                                                \
    for (int q = 0; q < 4; ++q)                                                      \
      *reinterpret_cast<float4*>(hp + (T0) + q * 4) =                                \
          make_float4(hb[q * 4], hb[q * 4 + 1], hb[q * 4 + 2], hb[q * 4 + 3]);       \
  } while (0)
  LOAD16(c0, 0);
  for (int i = 0; i < 15; ++i) {
    const int tb = i * 32;
    LOAD16(c1, tb + 16);
    PROC16(c0, tb);
    LOAD16(c0, tb + 32);
    PROC16(c1, tb + 16);
  }
  PROC16(c0, 480);
  {  // tail t = 496..499
    float c[4], hb[4];
#pragma unroll
    for (int u = 0; u < 4; ++u) c[u] = bf2f(cp[(size_t)(496 + u) * H0]);
#pragma unroll
    for (int u = 0; u < 4; ++u) {
      const float s = lif_step(v, c[u]);
      hb[u] = s;
      sp[(size_t)(496 + u + 1) * H0] = f2bf(s);
    }
    *reinterpret_cast<float4*>(hp + 496) = make_float4(hb[0], hb[1], hb[2], hb[3]);
  }
#undef LOAD16
#undef PROC16
}

// layers 1..4: preload N bf16 currents from LDS, then serial chain.
template<int N>
__device__ __forceinline__ void lif_dynb(float& v, float& rate, const unsigned short* cur,
                                         int cw, unsigned short* sd, int sw, float* hp,
                                         bool wsf) {
  float cr[16];
  const unsigned short* cp = cur;
#pragma unroll
  for (int u = 0; u < N; ++u) { cr[u] = bf2f(*cp); cp += cw; }
  float hb[16];
  unsigned short* sp = sd;
#pragma unroll
  for (int u = 0; u < N; ++u) {
    const float s = lif_step(v, cr[u]);
    hb[u] = s;
    if (wsf) *sp = f2bf(s);
    sp += sw;
    rate += s;
  }
#pragma unroll
  for (int q = 0; q < N / 4; ++q)
    *reinterpret_cast<float4*>(hp + q * 4) =
        make_float4(hb[q * 4], hb[q * 4 + 1], hb[q * 4 + 2], hb[q * 4 + 3]);
}

// ---------------- snn_tail14: fused gemm1..4 + scan1..4 + rates ---------------
// LDS-resident B-frags (loaded once), bf16 current buffers, A-frag loads hoisted
// to phase start (latency hidden under the scan + barrier drain).
__global__ __launch_bounds__(512, 1) void snn_tail14(
    const unsigned short* __restrict__ s0g, const unsigned short* __restrict__ Bf,
    float* __restrict__ out) {
  __shared__ __align__(16) unsigned short wl[85 * 512];         // 87 KB B-frags
  __shared__ __align__(16) unsigned short s1b[65 * SW1];
  __shared__ __align__(16) unsigned short s2b[65 * SW2];
  __shared__ __align__(16) unsigned short s3b[65 * SW3];
  __shared__ __align__(16) unsigned short c1b[64 * CW1];
  __shared__ __align__(16) unsigned short c2b[64 * CW2];
  __shared__ __align__(16) unsigned short c3b[64 * CW3];
  __shared__ __align__(16) unsigned short c4b[64 * CW4];

  const int b = blockIdx.x, tid = threadIdx.x;
  const int w = tid >> 6, lane = tid & 63, lr = lane & 15, lg = lane >> 4;
  const unsigned short* WL1 = wl;
  const unsigned short* WL2 = wl + 64 * 512;
  const unsigned short* WL3 = wl + 80 * 512;
  const unsigned short* WL4 = wl + 84 * 512;
  const unsigned short* s0b = s0g + (size_t)b * 512 * H0;

  // stage all B-fragments to LDS once
  {
    const uint4* src = reinterpret_cast<const uint4*>(Bf);
    uint4* dst = reinterpret_cast<uint4*>(wl);
    for (int i = tid; i < 85 * 512 / 8; i += 512) dst[i] = src[i];
  }

  float v = 0.0f, rate = 0.0f;
  int lay = 0, j = 0;
  const unsigned short* curb = nullptr;
  unsigned short* sb = s3b;
  float* hbase = nullptr;
  int cw = 0, sw = 0;
  bool wsf = false, sact = false;
  if (tid < 128) {
    lay = 1; j = tid; curb = c1b + j; sb = s1b; cw = CW1; sw = SW1; wsf = true;
    sact = true; hbase = out + H1_OFF + ((size_t)b * H1 + j) * TT;
  } else if (tid < 192) {
    lay = 2; j = tid - 128; curb = c2b + j; sb = s2b; cw = CW2; sw = SW2; wsf = true;
    sact = true; hbase = out + H2_OFF + ((size_t)b * H2 + j) * TT;
  } else if (tid < 224) {
    lay = 3; j = tid - 192; curb = c3b + j; sb = s3b; cw = CW3; sw = SW3; wsf = true;
    sact = true; hbase = out + H3_OFF + ((size_t)b * H3 + j) * TT;
  } else if (tid < 240) {
    lay = 4; j = tid - 224; curb = c4b + j; sb = s3b; cw = CW4; sw = 0; wsf = false;
    sact = (j < NOUT); hbase = out + OUT_OFF + ((size_t)b * NOUT + j) * TT;
  }
  __syncthreads();  // wl ready

  for (int p = 0; p < 12; ++p) {
    // -------- hoisted gemm1 A-frag loads (latency hides under scan) --------
    short8v a1[8];
    if (p <= 7) {
      const int tt = w >> 1;
      const unsigned short* ap = s0b + (size_t)(p * 64 + tt * 16 + lr) * H0 + lg * 8;
#pragma unroll
      for (int kc = 0; kc < 8; ++kc) a1[kc] = *reinterpret_cast<const short8v*>(ap + kc * 32);
    }
    // ================= scan part =================
    if (sact) {
      const int c = p - lay;
      if (c >= 0 && c <= 7) {
        if (wsf) sb[j] = (c == 0) ? (unsigned short)0 : sb[64 * sw + j];
        float* hp = hbase + c * 64;
        unsigned short* sbj = sb + j;
        if (c < 7) {
#pragma unroll
          for (int q = 0; q < 4; ++q)
            lif_dynb<16>(v, rate, curb + q * 16 * cw, cw, sbj + (q * 16 + 1) * sw, sw,
                         hp + q * 16, wsf);
        } else {
          lif_dynb<16>(v, rate, curb, cw, sbj + 1 * sw, sw, hp, wsf);
          lif_dynb<16>(v, rate, curb + 16 * cw, cw, sbj + 17 * sw, sw, hp + 16, wsf);
          lif_dynb<16>(v, rate, curb + 32 * cw, cw, sbj + 33 * sw, sw, hp + 32, wsf);
          lif_dynb<4>(v, rate, curb + 48 * cw, cw, sbj + 49 * sw, sw, hp + 48, wsf);
        }
      }
    }
    __syncthreads();
    // ================= gemm part (B-frags from LDS) =================
    if (p <= 7) {  // gemm1: s0g chunk p -> c1b
      const int tt = w >> 1, nb = (w & 1) * 4;
#pragma unroll
      for (int n4 = 0; n4 < 4; ++n4) {
        const int nt = nb + n4;
        f32x4 acc = (f32x4)0.0f;
#pragma unroll
        for (int kc = 0; kc < 8; ++kc) {
          const short8v bf = *reinterpret_cast<const short8v*>(WL1 + ((size_t)(nt * 8 + kc) * 64 + lane) * 8);
          acc = __builtin_amdgcn_mfma_f32_16x16x32_bf16(a1[kc], bf, acc, 0, 0, 0);
        }
        unsigned short* cd = c1b + (tt * 16 + lg * 4) * CW1 + nt * 16 + lr;
#pragma unroll
        for (int r = 0; r < 4; ++r) cd[r * CW1] = f2bf(acc[r]);
      }
    }
    if (p >= 1 && p <= 8) {  // gemm2: s1b -> c2b
      const int tt = w >> 1;
      short8v a[4];
      const unsigned short* ap = s1b + (tt * 16 + lr) * SW1 + lg * 8;
#pragma unroll
      for (int kc = 0; kc < 4; ++kc) a[kc] = *reinterpret_cast<const short8v*>(ap + kc * 32);
#pragma unroll
      for (int qi = 0; qi < 2; ++qi) {
        const int nt = (w & 1) * 2 + qi;
        f32x4 acc = (f32x4)0.0f;
#pragma unroll
        for (int kc = 0; kc < 4; ++kc) {
          const short8v bf = *reinterpret_cast<const short8v*>(WL2 + ((size_t)(nt * 4 + kc) * 64 + lane) * 8);
          acc = __builtin_amdgcn_mfma_f32_16x16x32_bf16(a[kc], bf, acc, 0, 0, 0);
        }
        unsigned short* cd = c2b + (tt * 16 + lg * 4) * CW2 + nt * 16 + lr;
#pragma unroll
        for (int r = 0; r < 4; ++r) cd[r * CW2] = f2bf(acc[r]);
      }
    }
    if (p >= 2 && p <= 9) {  // gemm3: s2b -> c3b
      const int tt = w >> 1, nt = w & 1;
      short8v a[2];
      const unsigned short* ap = s2b + (tt * 16 + lr) * SW2 + lg * 8;
#pragma unroll
      for (int kc = 0; kc < 2; ++kc) a[kc] = *reinterpret_cast<const short8v*>(ap + kc * 32);
      f32x4 acc = (f32x4)0.0f;
#pragma unroll
      for (int kc = 0; kc < 2; ++kc) {
        const short8v bf = *reinterpret_cast<const short8v*>(WL3 + ((size_t)(nt * 2 + kc) * 64 + lane) * 8);
        acc = __builtin_amdgcn_mfma_f32_16x16x32_bf16(a[kc], bf, acc, 0, 0, 0);
      }
      unsigned short* cd = c3b + (tt * 16 + lg * 4) * CW3 + nt * 16 + lr;
#pragma unroll
      for (int r = 0; r < 4; ++r) cd[r * CW3] = f2bf(acc[r]);
    }
    if (p >= 3 && p <= 10 && w < 4) {  // gemm4: s3b -> c4b
      const int tt = w;
      const unsigned short* ap = s3b + (tt * 16 + lr) * SW3 + lg * 8;
      const short8v a0 = *reinterpret_cast<const short8v*>(ap);
      const short8v bf = *reinterpret_cast<const short8v*>(WL4 + (size_t)lane * 8);
      f32x4 acc = (f32x4)0.0f;
      acc = __builtin_amdgcn_mfma_f32_16x16x32_bf16(a0, bf, acc, 0, 0, 0);
      unsigned short* cd = c4b + (tt * 16 + lg * 4) * CW4 + lr;
#pragma unroll
      for (int r = 0; r < 4; ++r) cd[r * CW4] = f2bf(acc[r]);
    }
    __syncthreads();
  }
  if (tid >= 224 && tid < 224 + NOUT)
    out[RATE_OFF + (size_t)b * NOUT + (tid - 224)] = rate * (1.0f / (float)TT);
}

extern "C" void kernel_launch(void* const* d_in, const int* in_sizes, int n_in,
                              void* d_out, int out_size, void* d_ws, size_t ws_size,
                              hipStream_t stream) {
  const float* X  = (const float*)d_in[0];
  const float* w0 = (const float*)d_in[1];
  const float* w1 = (const float*)d_in[2];
  const float* w2 = (const float*)d_in[3];
  const float* w3 = (const float*)d_in[4];
  const float* w4 = (const float*)d_in[5];
  float* out = (float*)d_out;

  uint8_t* ws = (uint8_t*)d_ws;
  const size_t SLOT = 33554432;
  unsigned short* cur0 = (unsigned short*)ws;                  // [b][TT][256] bf16
  unsigned short* s0g  = (unsigned short*)(ws + SLOT);         // [b][512][256] bf16
  unsigned short* Wf0  = (unsigned short*)(ws + 2 * SLOT);     // w0 A-frags
  unsigned short* Bf2  = Wf0 + (size_t)JTILES * KCH0 * 64 * 8; // w1..w4 B-frags

  pack_all<<<JTILES * KCH0 + 85, 64, 0, stream>>>(w0, w1, w2, w3, w4, Wf0, Bf2);
  gemm0<<<dim3(8, BATCH), 256, 0, stream>>>(X, Wf0, cur0);
  scan0<<<dim3(4, BATCH), 64, 0, stream>>>(cur0, s0g, out);
  snn_tail14<<<BATCH, 512, 0, stream>>>(s0g, Bf2, out);
}

// Round 9
// 190.089 us; speedup vs baseline: 1.8830x; 1.1478x over previous
//
#include <hip/hip_runtime.h>

#define NIN 784
#define H0 256
#define H1 128
#define H2 64
#define H3 32
#define NOUT 10
#define BATCH 128
#define TT 500
#define KCH0 25
#define JTILES 16

// LDS pads (all bf16): spike rows stride ≡4 mod 32 banks; cur rows padded +4
#define SW1 136
#define SW2 72
#define SW3 40
#define CW1 132
#define CW2 68
#define CW3 36
#define CW4 20
#define OW4 12

// d_out offsets (floats)
#define H1_OFF (BATCH * H0 * TT)
#define H2_OFF (H1_OFF + BATCH * H1 * TT)
#define H3_OFF (H2_OFF + BATCH * H2 * TT)
#define OUT_OFF (H3_OFF + BATCH * H3 * TT)
#define RATE_OFF (OUT_OFF + BATCH * NOUT * TT)

typedef __attribute__((ext_vector_type(8))) short short8v;
typedef __attribute__((ext_vector_type(4))) float f32x4;

__device__ __forceinline__ unsigned short f2bf(float f) {
  union { float f; unsigned u; } v; v.f = f;
  unsigned r = v.u + 0x7FFFu + ((v.u >> 16) & 1u);  // RNE
  return (unsigned short)(r >> 16);
}
__device__ __forceinline__ float bf2f(unsigned short b) {
  union { unsigned u; float f; } v; v.u = ((unsigned)b) << 16;
  return v.f;
}

// LIF step, shortened dependent chain: E=e^{-x}, s=1/(1+E), v*(1-s)=v*E/(1+E).
__device__ __forceinline__ float lif_step(float& v, float c) {
  v = 0.5f * (v + c);
  const float E = __expf(5.0f * (1.0f - v));
  const float r = 1.0f / (1.0f + E);
  v = v * E * r;
  return r;  // = s
}

// ---------------- pack_all: w0 -> A-frags, w1..w4 -> B-frags (verified) -------
__global__ void pack_all(const float* __restrict__ w0, const float* __restrict__ w1,
                         const float* __restrict__ w2, const float* __restrict__ w3,
                         const float* __restrict__ w4, unsigned short* __restrict__ Wf,
                         unsigned short* __restrict__ Bf) {
  const int bid = blockIdx.x, l = threadIdx.x;
  if (bid < JTILES * KCH0) {
    const int jt = bid / KCH0, kc = bid % KCH0;
    const int j = jt * 16 + (l & 15);
    const int kbase = kc * 32 + (l >> 4) * 8;
    unsigned v[4];
#pragma unroll
    for (int e = 0; e < 4; ++e) {
      const int k0 = kbase + e * 2;
      const float f0 = (k0 < NIN) ? fmaxf(w0[(size_t)k0 * H0 + j], 0.0f) : 0.0f;
      const float f1 = (k0 + 1 < NIN) ? fmaxf(w0[(size_t)(k0 + 1) * H0 + j], 0.0f) : 0.0f;
      v[e] = (unsigned)f2bf(f0) | ((unsigned)f2bf(f1) << 16);
    }
    uint4 o; o.x = v[0]; o.y = v[1]; o.z = v[2]; o.w = v[3];
    reinterpret_cast<uint4*>(Wf)[(size_t)bid * 64 + l] = o;
    return;
  }
  const int tile = bid - JTILES * KCH0;
  const float* w; int K, Nw, base, rel, KCH;
  if (tile < 64)      { w = w1; K = 256; Nw = 128; base = 0;        rel = tile;      KCH = 8; }
  else if (tile < 80) { w = w2; K = 128; Nw = 64;  base = 64 * 512; rel = tile - 64; KCH = 4; }
  else if (tile < 84) { w = w3; K = 64;  Nw = 32;  base = 80 * 512; rel = tile - 80; KCH = 2; }
  else                { w = w4; K = 32;  Nw = 10;  base = 84 * 512; rel = 0;         KCH = 1; }
  const int nt = rel / KCH, kc = rel % KCH;
  const int n = nt * 16 + (l & 15);
  const int kb = kc * 32 + (l >> 4) * 8;
  unsigned v[4];
#pragma unroll
  for (int e = 0; e < 4; ++e) {
    const int k0 = kb + e * 2;
    const float f0 = (n < Nw && k0 < K)     ? fmaxf(w[(size_t)k0 * Nw + n], 0.0f) : 0.0f;
    const float f1 = (n < Nw && k0 + 1 < K) ? fmaxf(w[(size_t)(k0 + 1) * Nw + n], 0.0f) : 0.0f;
    v[e] = (unsigned)f2bf(f0) | ((unsigned)f2bf(f1) << 16);
  }
  uint4 o; o.x = v[0]; o.y = v[1]; o.z = v[2]; o.w = v[3];
  *reinterpret_cast<uint4*>(Bf + base + ((size_t)rel * 64 + l) * 8) = o;
}

// ---------------- gemm0 (pipelined, __syncthreads; verified r3/r4) ------------
__global__ __launch_bounds__(256, 4) void gemm0(
    const float* __restrict__ X, const unsigned short* __restrict__ Wf,
    unsigned short* __restrict__ cur0) {
  const int ttile = blockIdx.x;
  const int b = blockIdx.y;
  const int tid = threadIdx.x;
  const int wave = tid >> 6, lane = tid & 63;
  const int t0 = ttile * 64;
  __shared__ unsigned short Xs[2][64 * 40];
  f32x4 acc[4][4];
#pragma unroll
  for (int i = 0; i < 4; ++i)
#pragma unroll
    for (int jj = 0; jj < 4; ++jj) acc[i][jj] = (f32x4)0.0f;

  const float* Xb = X + (size_t)b * NIN * TT;
  const int tt = tid & 63;
  const int kb = wave * 2;
  const int lrow = lane & 15, lgrp = lane >> 4;
  const int tgl = t0 + tt;
  const bool tin = tgl < TT;

  float r[8];
#pragma unroll
  for (int pp = 0; pp < 4; ++pp) {
    const int k = kb + pp * 8;
    r[pp * 2]     = tin ? Xb[(size_t)k * TT + tgl] : 0.0f;
    r[pp * 2 + 1] = tin ? Xb[(size_t)(k + 1) * TT + tgl] : 0.0f;
  }

  for (int kc = 0; kc < KCH0; ++kc) {
    unsigned short* xbuf = Xs[kc & 1];
#pragma unroll
    for (int pp = 0; pp < 4; ++pp) {
      const unsigned pk = (unsigned)f2bf(r[pp * 2]) | ((unsigned)f2bf(r[pp * 2 + 1]) << 16);
      *reinterpret_cast<unsigned*>(&xbuf[tt * 40 + kb + pp * 8]) = pk;
    }
    __syncthreads();
    if (kc + 1 < KCH0) {
      const int k0 = (kc + 1) * 32;
#pragma unroll
      for (int pp = 0; pp < 4; ++pp) {
        const int k = k0 + kb + pp * 8;
        r[pp * 2]     = (tin && k < NIN)     ? Xb[(size_t)k * TT + tgl] : 0.0f;
        r[pp * 2 + 1] = (tin && k + 1 < NIN) ? Xb[(size_t)(k + 1) * TT + tgl] : 0.0f;
      }
    }
    short8v afr[4], bfr[4];
#pragma unroll
    for (int jf = 0; jf < 4; ++jf) {
      const size_t off = ((size_t)((wave * 4 + jf) * KCH0 + kc) * 64 + lane) * 8;
      afr[jf] = *reinterpret_cast<const short8v*>(Wf + off);
    }
#pragma unroll
    for (int tf = 0; tf < 4; ++tf)
      bfr[tf] = *reinterpret_cast<const short8v*>(&xbuf[(tf * 16 + lrow) * 40 + lgrp * 8]);
#pragma unroll
    for (int jf = 0; jf < 4; ++jf)
#pragma unroll
      for (int tf = 0; tf < 4; ++tf)
        acc[jf][tf] = __builtin_amdgcn_mfma_f32_16x16x32_bf16(afr[jf], bfr[tf], acc[jf][tf], 0, 0, 0);
    __syncthreads();
  }

#pragma unroll
  for (int tf = 0; tf < 4; ++tf) {
    const int t = t0 + tf * 16 + lrow;
    if (t >= TT) continue;
    unsigned short* row = cur0 + ((size_t)b * TT + t) * H0;
#pragma unroll
    for (int jf = 0; jf < 4; ++jf) {
      const int j = wave * 64 + jf * 16 + lgrp * 4;
      const f32x4 a = acc[jf][tf];
      const unsigned p0 = (unsigned)f2bf(a[0]) | ((unsigned)f2bf(a[1]) << 16);
      const unsigned p1 = (unsigned)f2bf(a[2]) | ((unsigned)f2bf(a[3]) << 16);
      *reinterpret_cast<unsigned*>(row + j) = p0;
      *reinterpret_cast<unsigned*>(row + j + 2) = p1;
    }
  }
}

// ---------------- scan0 (standalone; 16-deep ping-pong, verified r7) ----------
__global__ __launch_bounds__(64) void scan0(
    const unsigned short* __restrict__ cur0, unsigned short* __restrict__ s0g,
    float* __restrict__ out) {
  const int b = blockIdx.y, jg = blockIdx.x, l = threadIdx.x;
  const int j = jg * 64 + l;
  const unsigned short* cp = cur0 + (size_t)b * TT * H0 + j;
  unsigned short* sp = s0g + (size_t)b * 512 * H0 + j;
  float* hp = out + ((size_t)b * H0 + j) * TT;
  sp[0] = 0;
  float v = 0.0f;
  float c0[16], c1[16];
#define LOAD16(D, T0) _Pragma("unroll") for (int u = 0; u < 16; ++u) (D)[u] = bf2f(cp[(size_t)((T0) + u) * H0]);
#define PROC16(C, T0)                                                                \
  do {                                                                               \
    float hb[16];                                                                    \
    _Pragma("unroll")                                                                \
    for (int u = 0; u < 16; ++u) {                                                   \
      const float s = lif_step(v, (C)[u]);                                           \
      hb[u] = s;                                                                     \
      sp[(size_t)((T0) + u + 1) * H0] = f2bf(s);                                     \
    }                                                                                \
    _Pragma("unroll")                                                                \
    for (int q = 0; q < 4; ++q)                                                      \
      *reinterpret_cast<float4*>(hp + (T0) + q * 4) =                                \
          make_float4(hb[q * 4], hb[q * 4 + 1], hb[q * 4 + 2], hb[q * 4 + 3]);       \
  } while (0)
  LOAD16(c0, 0);
  for (int i = 0; i < 15; ++i) {
    const int tb = i * 32;
    LOAD16(c1, tb + 16);
    PROC16(c0, tb);
    LOAD16(c0, tb + 32);
    PROC16(c1, tb + 16);
  }
  PROC16(c0, 480);
  {  // tail t = 496..499
    float c[4], hb[4];
#pragma unroll
    for (int u = 0; u < 4; ++u) c[u] = bf2f(cp[(size_t)(496 + u) * H0]);
#pragma unroll
    for (int u = 0; u < 4; ++u) {
      const float s = lif_step(v, c[u]);
      hb[u] = s;
      sp[(size_t)(496 + u + 1) * H0] = f2bf(s);
    }
    *reinterpret_cast<float4*>(hp + 496) = make_float4(hb[0], hb[1], hb[2], hb[3]);
  }
#undef LOAD16
#undef PROC16
}

// scan chain for layers 1..4: read N bf16 currents (stride cw), chain, write
// bf16 spikes to LDS (stride sw). No global writes (flush is cooperative).
template<int N>
__device__ __forceinline__ void lif_lds(float& v, float& rate, const unsigned short* cur,
                                        int cw, unsigned short* sd, int sw) {
  float cr[16];
  const unsigned short* cp = cur;
#pragma unroll
  for (int u = 0; u < N; ++u) { cr[u] = bf2f(*cp); cp += cw; }
#pragma unroll
  for (int u = 0; u < N; ++u) {
    const float s = lif_step(v, cr[u]);
    *sd = f2bf(s); sd += sw;
    rate += s;
  }
}

// ---------------- snn_tail14: fused gemm1..4 + scan1..4 + h-flush + rates -----
__global__ __launch_bounds__(512, 1) void snn_tail14(
    const unsigned short* __restrict__ s0g, const unsigned short* __restrict__ Bf,
    float* __restrict__ out) {
  __shared__ __align__(16) unsigned short wl[85 * 512];  // 87 KB B-frags
  __shared__ __align__(16) unsigned short s1b[65 * SW1];
  __shared__ __align__(16) unsigned short s2b[65 * SW2];
  __shared__ __align__(16) unsigned short s3b[65 * SW3];
  __shared__ __align__(16) unsigned short c1b[64 * CW1];
  __shared__ __align__(16) unsigned short c2b[64 * CW2];
  __shared__ __align__(16) unsigned short c3b[64 * CW3];
  __shared__ __align__(16) unsigned short c4b[64 * CW4];
  __shared__ __align__(16) unsigned short o4b[64 * OW4];

  const int b = blockIdx.x, tid = threadIdx.x;
  const int w = tid >> 6, lane = tid & 63, lr = lane & 15, lg = lane >> 4;
  const unsigned short* WL1 = wl;
  const unsigned short* WL2 = wl + 64 * 512;
  const unsigned short* WL3 = wl + 80 * 512;
  const unsigned short* WL4 = wl + 84 * 512;
  const unsigned short* s0b = s0g + (size_t)b * 512 * H0;

  // stage all B-fragments to LDS once
  {
    const uint4* src = reinterpret_cast<const uint4*>(Bf);
    uint4* dst = reinterpret_cast<uint4*>(wl);
    for (int i = tid; i < 85 * 512 / 8; i += 512) dst[i] = src[i];
  }

  float v = 0.0f, rate = 0.0f;
  int lay = 0, j = 0;
  const unsigned short* curb = nullptr;
  unsigned short* sb = s3b;
  int cw = 0, sw = 0;
  bool srow0 = false, sact = false;
  unsigned short* sdbase = nullptr;  // spike dest for step 0 of a chunk
  if (tid < 128) {
    lay = 1; j = tid; curb = c1b + j; sb = s1b; cw = CW1; sw = SW1;
    srow0 = true; sact = true; sdbase = s1b + j + SW1;
  } else if (tid < 192) {
    lay = 2; j = tid - 128; curb = c2b + j; sb = s2b; cw = CW2; sw = SW2;
    srow0 = true; sact = true; sdbase = s2b + j + SW2;
  } else if (tid < 224) {
    lay = 3; j = tid - 192; curb = c3b + j; sb = s3b; cw = CW3; sw = SW3;
    srow0 = true; sact = true; sdbase = s3b + j + SW3;
  } else if (tid < 240) {
    lay = 4; j = tid - 224; curb = c4b + j; cw = CW4; sw = OW4;
    srow0 = false; sact = (j < NOUT); sdbase = o4b + j;
  }
  __syncthreads();  // wl ready

  for (int p = 0; p < 12; ++p) {
    // -------- hoisted gemm1 A-frag loads (latency hides under scan) --------
    short8v a1[8];
    if (p <= 7) {
      const int tt = w >> 1;
      const unsigned short* ap = s0b + (size_t)(p * 64 + tt * 16 + lr) * H0 + lg * 8;
#pragma unroll
      for (int kc = 0; kc < 8; ++kc) a1[kc] = *reinterpret_cast<const short8v*>(ap + kc * 32);
    }
    // ================= scan part =================
    if (sact) {
      const int c = p - lay;
      if (c >= 0 && c <= 7) {
        if (srow0) sb[j] = (c == 0) ? (unsigned short)0 : sb[64 * sw + j];
        if (c < 7) {
#pragma unroll
          for (int q = 0; q < 4; ++q)
            lif_lds<16>(v, rate, curb + q * 16 * cw, cw, sdbase + q * 16 * sw, sw);
        } else {
          lif_lds<16>(v, rate, curb, cw, sdbase, sw);
          lif_lds<16>(v, rate, curb + 16 * cw, cw, sdbase + 16 * sw, sw);
          lif_lds<16>(v, rate, curb + 32 * cw, cw, sdbase + 32 * sw, sw);
          lif_lds<4>(v, rate, curb + 48 * cw, cw, sdbase + 48 * sw, sw);
        }
      }
    }
    __syncthreads();
    // ================= gemm part (B-frags from LDS) =================
    if (p <= 7) {  // gemm1: s0g chunk p -> c1b
      const int tt = w >> 1, nb = (w & 1) * 4;
#pragma unroll
      for (int n4 = 0; n4 < 4; ++n4) {
        const int nt = nb + n4;
        f32x4 acc = (f32x4)0.0f;
#pragma unroll
        for (int kc = 0; kc < 8; ++kc) {
          const short8v bf = *reinterpret_cast<const short8v*>(WL1 + ((size_t)(nt * 8 + kc) * 64 + lane) * 8);
          acc = __builtin_amdgcn_mfma_f32_16x16x32_bf16(a1[kc], bf, acc, 0, 0, 0);
        }
        unsigned short* cd = c1b + (tt * 16 + lg * 4) * CW1 + nt * 16 + lr;
#pragma unroll
        for (int r = 0; r < 4; ++r) cd[r * CW1] = f2bf(acc[r]);
      }
    }
    if (p >= 1 && p <= 8) {  // gemm2: s1b -> c2b
      const int tt = w >> 1;
      short8v a[4];
      const unsigned short* ap = s1b + (tt * 16 + lr) * SW1 + lg * 8;
#pragma unroll
      for (int kc = 0; kc < 4; ++kc) a[kc] = *reinterpret_cast<const short8v*>(ap + kc * 32);
#pragma unroll
      for (int qi = 0; qi < 2; ++qi) {
        const int nt = (w & 1) * 2 + qi;
        f32x4 acc = (f32x4)0.0f;
#pragma unroll
        for (int kc = 0; kc < 4; ++kc) {
          const short8v bf = *reinterpret_cast<const short8v*>(WL2 + ((size_t)(nt * 4 + kc) * 64 + lane) * 8);
          acc = __builtin_amdgcn_mfma_f32_16x16x32_bf16(a[kc], bf, acc, 0, 0, 0);
        }
        unsigned short* cd = c2b + (tt * 16 + lg * 4) * CW2 + nt * 16 + lr;
#pragma unroll
        for (int r = 0; r < 4; ++r) cd[r * CW2] = f2bf(acc[r]);
      }
    }
    if (p >= 2 && p <= 9) {  // gemm3: s2b -> c3b
      const int tt = w >> 1, nt = w & 1;
      short8v a[2];
      const unsigned short* ap = s2b + (tt * 16 + lr) * SW2 + lg * 8;
#pragma unroll
      for (int kc = 0; kc < 2; ++kc) a[kc] = *reinterpret_cast<const short8v*>(ap + kc * 32);
      f32x4 acc = (f32x4)0.0f;
#pragma unroll
      for (int kc = 0; kc < 2; ++kc) {
        const short8v bf = *reinterpret_cast<const short8v*>(WL3 + ((size_t)(nt * 2 + kc) * 64 + lane) * 8);
        acc = __builtin_amdgcn_mfma_f32_16x16x32_bf16(a[kc], bf, acc, 0, 0, 0);
      }
      unsigned short* cd = c3b + (tt * 16 + lg * 4) * CW3 + nt * 16 + lr;
#pragma unroll
      for (int r = 0; r < 4; ++r) cd[r * CW3] = f2bf(acc[r]);
    }
    if (p >= 3 && p <= 10 && w < 4) {  // gemm4: s3b -> c4b
      const int tt = w;
      const unsigned short* ap = s3b + (tt * 16 + lr) * SW3 + lg * 8;
      const short8v a0 = *reinterpret_cast<const short8v*>(ap);
      const short8v bf = *reinterpret_cast<const short8v*>(WL4 + (size_t)lane * 8);
      f32x4 acc = (f32x4)0.0f;
      acc = __builtin_amdgcn_mfma_f32_16x16x32_bf16(a0, bf, acc, 0, 0, 0);
      unsigned short* cd = c4b + (tt * 16 + lg * 4) * CW4 + lr;
#pragma unroll
      for (int r = 0; r < 4; ++r) cd[r * CW4] = f2bf(acc[r]);
    }
    // ================= cooperative transposed h-flush =================
    // lane = t (coalesced stores), rows j split across the 8 waves.
    if (p >= 1 && p <= 8) {  // h1 chunk c = p-1 from s1b slots 1..64
      const int c = p - 1;
      const int nt = (c == 7) ? 52 : 64;
      if (lane < nt) {
        float* o1 = out + H1_OFF + ((size_t)b * H1 + w * 16) * TT + c * 64 + lane;
#pragma unroll
        for (int rr = 0; rr < 16; ++rr)
          o1[(size_t)rr * TT] = bf2f(s1b[(lane + 1) * SW1 + w * 16 + rr]);
      }
    }
    if (p >= 2 && p <= 9) {  // h2 chunk c = p-2
      const int c = p - 2;
      const int nt = (c == 7) ? 52 : 64;
      if (lane < nt) {
        float* o2 = out + H2_OFF + ((size_t)b * H2 + w * 8) * TT + c * 64 + lane;
#pragma unroll
        for (int rr = 0; rr < 8; ++rr)
          o2[(size_t)rr * TT] = bf2f(s2b[(lane + 1) * SW2 + w * 8 + rr]);
      }
    }
    if (p >= 3 && p <= 10) {  // h3 chunk c = p-3
      const int c = p - 3;
      const int nt = (c == 7) ? 52 : 64;
      if (lane < nt) {
        float* o3 = out + H3_OFF + ((size_t)b * H3 + w * 4) * TT + c * 64 + lane;
#pragma unroll
        for (int rr = 0; rr < 4; ++rr)
          o3[(size_t)rr * TT] = bf2f(s3b[(lane + 1) * SW3 + w * 4 + rr]);
      }
    }
    if (p >= 4 && p <= 11 && w < 5) {  // output spikes chunk c = p-4 from o4b
      const int c = p - 4;
      const int nt = (c == 7) ? 52 : 64;
      if (lane < nt) {
#pragma unroll
        for (int rr = 0; rr < 2; ++rr) {
          const int jj = w * 2 + rr;
          out[OUT_OFF + ((size_t)b * NOUT + jj) * TT + c * 64 + lane] =
              bf2f(o4b[lane * OW4 + jj]);
        }
      }
    }
    __syncthreads();
  }
  if (tid >= 224 && tid < 224 + NOUT)
    out[RATE_OFF + (size_t)b * NOUT + (tid - 224)] = rate * (1.0f / (float)TT);
}

extern "C" void kernel_launch(void* const* d_in, const int* in_sizes, int n_in,
                              void* d_out, int out_size, void* d_ws, size_t ws_size,
                              hipStream_t stream) {
  const float* X  = (const float*)d_in[0];
  const float* w0 = (const float*)d_in[1];
  const float* w1 = (const float*)d_in[2];
  const float* w2 = (const float*)d_in[3];
  const float* w3 = (const float*)d_in[4];
  const float* w4 = (const float*)d_in[5];
  float* out = (float*)d_out;

  uint8_t* ws = (uint8_t*)d_ws;
  const size_t SLOT = 33554432;
  unsigned short* cur0 = (unsigned short*)ws;                  // [b][TT][256] bf16
  unsigned short* s0g  = (unsigned short*)(ws + SLOT);         // [b][512][256] bf16
  unsigned short* Wf0  = (unsigned short*)(ws + 2 * SLOT);     // w0 A-frags
  unsigned short* Bf2  = Wf0 + (size_t)JTILES * KCH0 * 64 * 8; // w1..w4 B-frags

  pack_all<<<JTILES * KCH0 + 85, 64, 0, stream>>>(w0, w1, w2, w3, w4, Wf0, Bf2);
  gemm0<<<dim3(8, BATCH), 256, 0, stream>>>(X, Wf0, cur0);
  scan0<<<dim3(4, BATCH), 64, 0, stream>>>(cur0, s0g, out);
  snn_tail14<<<BATCH, 512, 0, stream>>>(s0g, Bf2, out);
}